// Round 2
// baseline (367.667 us; speedup 1.0000x reference)
//
#include <hip/hip_runtime.h>
#include <float.h>
#include <math.h>

// Problem constants (from reference setup_inputs): B=8, S=4096, C=1024, H=64
constexpr int Bn = 8;
constexpr int Sn = 4096;
constexpr int Cn = 1024;
constexpr int Hn = 64;

// ---------------------------------------------------------------------------
// K1: per-(batch, S-tile) masked sum/max partial reduction over the sequence.
// Each block handles `rows_per_tile` contiguous rows of one batch; thread t
// owns channels [4t, 4t+4). Mask is wave-uniform per row -> no divergence,
// and unmasked rows are never loaded (saves ~50% of pass-1 HBM traffic).
// Partials land in private ws slots -> no init / no atomics needed.
// ---------------------------------------------------------------------------
__global__ __launch_bounds__(256) void k_reduce(
    const float* __restrict__ x, const int* __restrict__ mask,
    float* __restrict__ psum, float* __restrict__ pmax, float* __restrict__ pcnt,
    int tiles, int rows_per_tile)
{
    const int b    = blockIdx.y;
    const int tile = blockIdx.x;
    const int t    = threadIdx.x;
    const int s0   = tile * rows_per_tile;
    const float* xb = x + (size_t)b * Sn * Cn;

    __shared__ int smask[512];  // rows_per_tile <= 512 always (tiles >= 8)
    for (int i = t; i < rows_per_tile; i += 256) smask[i] = mask[b * Sn + s0 + i];
    __syncthreads();

    float4 sum = make_float4(0.f, 0.f, 0.f, 0.f);
    float4 mx  = make_float4(-FLT_MAX, -FLT_MAX, -FLT_MAX, -FLT_MAX);
    int cnt = 0;
    const int c4 = t * 4;
    for (int r = 0; r < rows_per_tile; ++r) {
        if (smask[r]) {
            const float4 v = *reinterpret_cast<const float4*>(
                xb + (size_t)(s0 + r) * Cn + c4);
            sum.x += v.x; sum.y += v.y; sum.z += v.z; sum.w += v.w;
            mx.x = fmaxf(mx.x, v.x); mx.y = fmaxf(mx.y, v.y);
            mx.z = fmaxf(mx.z, v.z); mx.w = fmaxf(mx.w, v.w);
            ++cnt;
        }
    }
    const size_t base = ((size_t)b * tiles + tile) * Cn + c4;
    *reinterpret_cast<float4*>(psum + base) = sum;
    *reinterpret_cast<float4*>(pmax + base) = mx;
    if (t == 0) pcnt[b * tiles + tile] = (float)cnt;
}

// ---------------------------------------------------------------------------
// K2: finalize reduction + the tiny MLP + sigmoid. One block per batch.
// mlp(mean)+mlp(max) = (relu(h_mean)+relu(h_max)) @ W1^T  (linear combine).
// ~0.5 MFLOP per block -> latency-bound but negligible.
// ---------------------------------------------------------------------------
__global__ __launch_bounds__(256) void k_mlp(
    const float* __restrict__ psum, const float* __restrict__ pmax,
    const float* __restrict__ pcnt,
    const float* __restrict__ W0, const float* __restrict__ W1,
    float* __restrict__ a, int tiles)
{
    const int b = blockIdx.x;
    const int t = threadIdx.x;
    __shared__ float mean_s[Cn];
    __shared__ float max_s[Cn];
    __shared__ float r_s[2 * Hn];

    float cntf = 0.f;
    for (int i = 0; i < tiles; ++i) cntf += pcnt[b * tiles + i];
    cntf = fmaxf(cntf, 1.f);

    for (int c = t; c < Cn; c += 256) {
        float s = 0.f, m = -FLT_MAX;
        for (int i = 0; i < tiles; ++i) {
            const size_t base = ((size_t)b * tiles + i) * Cn + c;
            s += psum[base];
            m = fmaxf(m, pmax[base]);
        }
        mean_s[c] = s / cntf;
        max_s[c]  = m;
    }
    __syncthreads();

    if (t < 2 * Hn) {
        const int j = t & (Hn - 1);
        const float* v = (t < Hn) ? mean_s : max_s;  // LDS broadcast reads
        const float* w = W0 + j * Cn;
        float h = 0.f;
        for (int c = 0; c < Cn; ++c) h = fmaf(v[c], w[c], h);
        r_s[t] = fmaxf(h, 0.f);
    }
    __syncthreads();

    for (int c = t; c < Cn; c += 256) {
        float acc = 0.f;
        const float* w1 = W1 + c * Hn;
        for (int j = 0; j < Hn; ++j) acc = fmaf(r_s[j] + r_s[Hn + j], w1[j], acc);
        a[b * Cn + c] = 1.f / (1.f + expf(-acc));
    }
}

// ---------------------------------------------------------------------------
// K3: out = x * a (a broadcast over S). float4 grid-stride, pure BW.
// S*C = 2^22 -> batch index is a shift; C=1024 -> channel is a mask.
// ---------------------------------------------------------------------------
__global__ __launch_bounds__(256) void k_scale(
    const float* __restrict__ x, const float* __restrict__ a,
    float* __restrict__ out)
{
    const size_t total4 = (size_t)Bn * Sn * Cn / 4;
    const size_t stride = (size_t)gridDim.x * blockDim.x;
    for (size_t i = (size_t)blockIdx.x * blockDim.x + threadIdx.x;
         i < total4; i += stride) {
        const size_t e = i * 4;
        const int c = (int)(e & (size_t)(Cn - 1));
        const int b = (int)(e >> 22);  // / (S*C)
        float4 v = reinterpret_cast<const float4*>(x)[i];
        const float4 av = *reinterpret_cast<const float4*>(a + b * Cn + c);
        v.x *= av.x; v.y *= av.y; v.z *= av.z; v.w *= av.w;
        reinterpret_cast<float4*>(out)[i] = v;
    }
}

extern "C" void kernel_launch(void* const* d_in, const int* in_sizes, int n_in,
                              void* d_out, int out_size, void* d_ws, size_t ws_size,
                              hipStream_t stream)
{
    const float* x    = (const float*)d_in[0];
    const int*   mask = (const int*)d_in[1];
    const float* W0   = (const float*)d_in[2];
    const float* W1   = (const float*)d_in[3];
    float* out = (float*)d_out;

    // Pick the largest tile count whose partials fit in d_ws (64 -> 4.2 MB).
    int tiles = 64;
    while (tiles > 8) {
        size_t need = ((size_t)2 * Bn * tiles * Cn + Bn * tiles + Bn * Cn)
                      * sizeof(float);
        if (need <= ws_size) break;
        tiles >>= 1;
    }
    const int rows = Sn / tiles;

    float* psum = (float*)d_ws;
    float* pmax = psum + (size_t)Bn * tiles * Cn;
    float* pcnt = pmax + (size_t)Bn * tiles * Cn;
    float* a    = pcnt + (size_t)Bn * tiles;

    k_reduce<<<dim3(tiles, Bn), 256, 0, stream>>>(x, mask, psum, pmax, pcnt,
                                                  tiles, rows);
    k_mlp<<<Bn, 256, 0, stream>>>(psum, pmax, pcnt, W0, W1, a, tiles);
    k_scale<<<2048, 256, 0, stream>>>(x, a, out);
}

// Round 4
// 279.075 us; speedup vs baseline: 1.3174x; 1.3174x over previous
//
#include <hip/hip_runtime.h>
#include <float.h>
#include <math.h>

// Problem constants: B=8, S=4096, C=1024, H=64
constexpr int Bn = 8;
constexpr int Sn = 4096;
constexpr int Cn = 1024;
constexpr int Hn = 64;

// Native clang vector (HIP's float4 is a struct and is rejected by
// __builtin_nontemporal_store).
typedef float f32x4 __attribute__((ext_vector_type(4)));

// ---------------------------------------------------------------------------
// K1: per-(batch, S-tile) masked sum/max partials. Masked row indices are
// compacted into LDS first (order-free), so the load loop is branchless and
// 4-way unrolled -> 4+ loads in flight instead of one per data-dependent
// branch. Thread t owns channels [4t, 4t+4) -> one full coalesced row per
// load iteration. Partials go to private ws slots (no init, no atomics).
// ---------------------------------------------------------------------------
__global__ __launch_bounds__(256) void k_reduce(
    const float* __restrict__ x, const int* __restrict__ mask,
    float* __restrict__ psum, float* __restrict__ pmax, float* __restrict__ pcnt,
    int tiles, int rows_per_tile)
{
    const int b    = blockIdx.y;
    const int tile = blockIdx.x;
    const int t    = threadIdx.x;
    const int s0   = tile * rows_per_tile;
    const float* xb = x + (size_t)b * Sn * Cn;

    __shared__ int srows[512];
    __shared__ int scount;
    if (t == 0) scount = 0;
    __syncthreads();
    for (int i = t; i < rows_per_tile; i += 256)
        if (mask[b * Sn + s0 + i]) srows[atomicAdd(&scount, 1)] = s0 + i;
    __syncthreads();
    const int n  = scount;
    const int c4 = t * 4;

    f32x4 sA = 0.f, sB = 0.f, sC = 0.f, sD = 0.f;
    f32x4 mA = -FLT_MAX, mB = -FLT_MAX, mC = -FLT_MAX, mD = -FLT_MAX;

    int k = 0;
    for (; k + 4 <= n; k += 4) {
        const f32x4 v0 = *reinterpret_cast<const f32x4*>(xb + (size_t)srows[k + 0] * Cn + c4);
        const f32x4 v1 = *reinterpret_cast<const f32x4*>(xb + (size_t)srows[k + 1] * Cn + c4);
        const f32x4 v2 = *reinterpret_cast<const f32x4*>(xb + (size_t)srows[k + 2] * Cn + c4);
        const f32x4 v3 = *reinterpret_cast<const f32x4*>(xb + (size_t)srows[k + 3] * Cn + c4);
        sA += v0;
        mA.x = fmaxf(mA.x, v0.x); mA.y = fmaxf(mA.y, v0.y); mA.z = fmaxf(mA.z, v0.z); mA.w = fmaxf(mA.w, v0.w);
        sB += v1;
        mB.x = fmaxf(mB.x, v1.x); mB.y = fmaxf(mB.y, v1.y); mB.z = fmaxf(mB.z, v1.z); mB.w = fmaxf(mB.w, v1.w);
        sC += v2;
        mC.x = fmaxf(mC.x, v2.x); mC.y = fmaxf(mC.y, v2.y); mC.z = fmaxf(mC.z, v2.z); mC.w = fmaxf(mC.w, v2.w);
        sD += v3;
        mD.x = fmaxf(mD.x, v3.x); mD.y = fmaxf(mD.y, v3.y); mD.z = fmaxf(mD.z, v3.z); mD.w = fmaxf(mD.w, v3.w);
    }
    for (; k < n; ++k) {
        const f32x4 v0 = *reinterpret_cast<const f32x4*>(xb + (size_t)srows[k] * Cn + c4);
        sA += v0;
        mA.x = fmaxf(mA.x, v0.x); mA.y = fmaxf(mA.y, v0.y); mA.z = fmaxf(mA.z, v0.z); mA.w = fmaxf(mA.w, v0.w);
    }
    f32x4 sum = (sA + sB) + (sC + sD);
    f32x4 mx;
    mx.x = fmaxf(fmaxf(mA.x, mB.x), fmaxf(mC.x, mD.x));
    mx.y = fmaxf(fmaxf(mA.y, mB.y), fmaxf(mC.y, mD.y));
    mx.z = fmaxf(fmaxf(mA.z, mB.z), fmaxf(mC.z, mD.z));
    mx.w = fmaxf(fmaxf(mA.w, mB.w), fmaxf(mC.w, mD.w));

    const size_t base = ((size_t)b * tiles + tile) * Cn + c4;
    *reinterpret_cast<f32x4*>(psum + base) = sum;
    *reinterpret_cast<f32x4*>(pmax + base) = mx;
    if (t == 0) pcnt[b * tiles + tile] = (float)n;
}

// ---------------------------------------------------------------------------
// K2: parallel finalize of the partials. Grid (B, 32): block owns 32 channels
// of one batch; 8 tile-groups per block reduce in parallel, LDS-combined.
// mm[b][0][c] = total sum (not yet divided), mm[b][1][c] = max.
// ---------------------------------------------------------------------------
__global__ __launch_bounds__(256) void k_final(
    const float* __restrict__ psum, const float* __restrict__ pmax,
    float* __restrict__ mm, int tiles)
{
    const int b     = blockIdx.x;
    const int chunk = blockIdx.y;
    const int t     = threadIdx.x;
    const int lc    = t & 31;
    const int g     = t >> 5;          // 8 tile-groups
    const int c     = chunk * 32 + lc;
    const int iters = tiles >> 3;      // tiles divisible by 8

    float s = 0.f, m = -FLT_MAX;
#pragma unroll 4
    for (int k = 0; k < iters; ++k) {
        const int i = g * iters + k;
        const size_t base = ((size_t)(b * tiles + i)) * Cn + c;
        s += psum[base];
        m = fmaxf(m, pmax[base]);
    }
    __shared__ float ssum[8][32];
    __shared__ float smax[8][32];
    ssum[g][lc] = s;
    smax[g][lc] = m;
    __syncthreads();
    if (t < 32) {
        float ts = ssum[0][t], tm = smax[0][t];
#pragma unroll
        for (int gg = 1; gg < 8; ++gg) {
            ts += ssum[gg][t];
            tm = fmaxf(tm, smax[gg][t]);
        }
        mm[(size_t)b * 2 * Cn + chunk * 32 + t]      = ts;
        mm[(size_t)b * 2 * Cn + Cn + chunk * 32 + t] = tm;
    }
}

// ---------------------------------------------------------------------------
// K3: the tiny MLP, one block per batch. Hidden dots are wave-parallel:
// each wave handles j, lanes cover 16 coalesced W0 elements each (stride-64
// lane-major), both mean- and max-dots share the W0 load, shfl_xor reduce.
// mlp(mean)+mlp(max) = (relu(h_mean)+relu(h_max)) @ W1^T.
// ---------------------------------------------------------------------------
__global__ __launch_bounds__(256) void k_mlp2(
    const float* __restrict__ mm, const float* __restrict__ pcnt,
    const float* __restrict__ W0, const float* __restrict__ W1,
    float* __restrict__ a, int tiles)
{
    const int b = blockIdx.x;
    const int t = threadIdx.x;
    __shared__ float vmean[Cn];
    __shared__ float vmax[Cn];
    __shared__ float rc[Hn];
    __shared__ float sc[256];

    sc[t] = (t < tiles) ? pcnt[b * tiles + t] : 0.f;
    __syncthreads();
    for (int o = 128; o > 0; o >>= 1) {
        if (t < o) sc[t] += sc[t + o];
        __syncthreads();
    }
    const float inv = 1.f / fmaxf(sc[0], 1.f);

    for (int c = t; c < Cn; c += 256) {
        vmean[c] = mm[(size_t)b * 2 * Cn + c] * inv;
        vmax[c]  = mm[(size_t)b * 2 * Cn + Cn + c];
    }
    __syncthreads();

    const int lane = t & 63;
    const int w    = t >> 6;
    for (int j = w; j < Hn; j += 4) {
        float am = 0.f, ax = 0.f;
#pragma unroll
        for (int k = 0; k < 16; ++k) {
            const float w0 = W0[j * Cn + k * 64 + lane];
            am = fmaf(vmean[k * 64 + lane], w0, am);
            ax = fmaf(vmax[k * 64 + lane], w0, ax);
        }
        for (int o = 32; o > 0; o >>= 1) {
            am += __shfl_xor(am, o);
            ax += __shfl_xor(ax, o);
        }
        if (lane == 0) rc[j] = fmaxf(am, 0.f) + fmaxf(ax, 0.f);
    }
    __syncthreads();

    for (int c = t; c < Cn; c += 256) {
        const f32x4* w1 = reinterpret_cast<const f32x4*>(W1 + c * Hn);
        float a0 = 0.f, a1 = 0.f, a2 = 0.f, a3 = 0.f;
#pragma unroll
        for (int q = 0; q < 16; ++q) {
            const f32x4 wv = w1[q];
            a0 = fmaf(rc[4 * q + 0], wv.x, a0);
            a1 = fmaf(rc[4 * q + 1], wv.y, a1);
            a2 = fmaf(rc[4 * q + 2], wv.z, a2);
            a3 = fmaf(rc[4 * q + 3], wv.w, a3);
        }
        const float acc = (a0 + a1) + (a2 + a3);
        a[b * Cn + c] = 1.f / (1.f + expf(-acc));
    }
}

// ---------------------------------------------------------------------------
// K4: out = x * a (a broadcast over S). f32x4, 4096 blocks, nontemporal
// stores (out is never re-read; keep x/L3 residency for the read stream).
// ---------------------------------------------------------------------------
__global__ __launch_bounds__(256) void k_scale(
    const float* __restrict__ x, const float* __restrict__ a,
    float* __restrict__ out)
{
    const size_t total4 = (size_t)Bn * Sn * Cn / 4;
    const size_t stride = (size_t)gridDim.x * blockDim.x;
    for (size_t i = (size_t)blockIdx.x * blockDim.x + threadIdx.x;
         i < total4; i += stride) {
        const size_t e = i * 4;
        const int c = (int)(e & (size_t)(Cn - 1));
        const int b = (int)(e >> 22);  // / (S*C)
        f32x4 v = reinterpret_cast<const f32x4*>(x)[i];
        const f32x4 av = *reinterpret_cast<const f32x4*>(a + b * Cn + c);
        v *= av;
        __builtin_nontemporal_store(v, reinterpret_cast<f32x4*>(out) + i);
    }
}

extern "C" void kernel_launch(void* const* d_in, const int* in_sizes, int n_in,
                              void* d_out, int out_size, void* d_ws, size_t ws_size,
                              hipStream_t stream)
{
    const float* x    = (const float*)d_in[0];
    const int*   mask = (const int*)d_in[1];
    const float* W0   = (const float*)d_in[2];
    const float* W1   = (const float*)d_in[3];
    float* out = (float*)d_out;

    // Largest tile count whose partials fit in d_ws (128 -> ~8.5 MB).
    int tiles = 128;
    while (tiles > 8) {
        size_t need = ((size_t)2 * Bn * tiles * Cn + (size_t)Bn * tiles
                       + (size_t)Bn * 2 * Cn + (size_t)Bn * Cn) * sizeof(float);
        if (need <= ws_size) break;
        tiles >>= 1;
    }
    const int rows = Sn / tiles;

    float* psum = (float*)d_ws;
    float* pmax = psum + (size_t)Bn * tiles * Cn;
    float* pcnt = pmax + (size_t)Bn * tiles * Cn;
    float* mm   = pcnt + (size_t)Bn * tiles;
    float* a    = mm + (size_t)Bn * 2 * Cn;

    k_reduce<<<dim3(tiles, Bn), 256, 0, stream>>>(x, mask, psum, pmax, pcnt,
                                                  tiles, rows);
    k_final<<<dim3(Bn, Cn / 32), 256, 0, stream>>>(psum, pmax, mm, tiles);
    k_mlp2<<<Bn, 256, 0, stream>>>(mm, pcnt, W0, W1, a, tiles);
    k_scale<<<4096, 256, 0, stream>>>(x, a, out);
}